// Round 21
// baseline (1576.708 us; speedup 1.0000x reference)
//
#include <hip/hip_runtime.h>
#include <hip/hip_bf16.h>

namespace {
constexpr int kD = 1024, kE = 8, kH = 4096;
constexpr int kN = 16384;     // B*T tokens
constexpr int kCap = 4096;    // N*TOP_K/E * CAPACITY_FACTOR
}

typedef __attribute__((ext_vector_type(8))) short short8;
typedef __attribute__((ext_vector_type(4))) float f32x4;

static __device__ __forceinline__ unsigned short f2bf(float f) {
    __hip_bfloat16 h = __float2bfloat16(f);   // RNE
    unsigned short s;
    __builtin_memcpy(&s, &h, 2);
    return s;
}

static __device__ __forceinline__ void gload_lds16(const unsigned short* g, unsigned short* l) {
    __builtin_amdgcn_global_load_lds(
        (const __attribute__((address_space(1))) unsigned int*)g,
        (__attribute__((address_space(3))) unsigned int*)l, 16, 0, 0);
}

// ---------------- fused transpose+convert for W1 AND W2 (one launch) ----------------
__global__ __launch_bounds__(256) void moe_tcvt2(
    const float* __restrict__ W1, unsigned short* __restrict__ W1t,
    const float* __restrict__ W2, unsigned short* __restrict__ W2t)
{
    const int z = blockIdx.z;
    const float* src;
    unsigned short* dst;
    int R, C, bx, by;
    if (z < kE) {
        src = W1 + (size_t)z * kD * kH; dst = W1t + (size_t)z * kD * kH;
        R = kD; C = kH; bx = blockIdx.x % (kH / 64); by = blockIdx.x / (kH / 64);
    } else {
        src = W2 + (size_t)(z - kE) * kH * kD; dst = W2t + (size_t)(z - kE) * kH * kD;
        R = kH; C = kD; bx = blockIdx.x % (kD / 64); by = blockIdx.x / (kD / 64);
    }
    const int c0 = bx * 64, r0 = by * 64;
    __shared__ float t[64][68];
    const int tid = (int)threadIdx.x;
    const int tr = tid >> 2;
    const int tc = (tid & 3) * 16;
    #pragma unroll
    for (int j = 0; j < 4; ++j) {
        const float4 v = *(const float4*)(src + (size_t)(r0 + tr) * C + c0 + tc + j * 4);
        *(float4*)&t[tr][tc + j * 4] = v;
    }
    __syncthreads();
    unsigned short o[16];
    #pragma unroll
    for (int j = 0; j < 16; ++j) o[j] = f2bf(t[tc + j][tr]);
    unsigned short* dp = dst + (size_t)(c0 + tr) * R + r0 + tc;
    *(short8*)dp = *(const short8*)&o[0];
    *(short8*)(dp + 8) = *(const short8*)&o[8];
}

// ---------------- router (fused x->bf16 emit + out zeroing) ----------------
__global__ __launch_bounds__(256) void moe_router(
    const float* __restrict__ x, const float* __restrict__ noise_raw,
    const float* __restrict__ Wr, const float* __restrict__ br,
    const float* __restrict__ Wn, const float* __restrict__ bn,
    int2* __restrict__ topIdx, float2* __restrict__ topProb,
    unsigned short* __restrict__ xb, float* __restrict__ out)
{
    const int wave = threadIdx.x >> 6;
    const int lane = threadIdx.x & 63;
    const int n = blockIdx.x * 4 + wave;
    const float* xr = x + (size_t)n * kD;
    unsigned short* xbr = xb + (size_t)n * kD;
    float* outr = out + (size_t)n * kD;

    float accr[kE], accn[kE];
    #pragma unroll
    for (int e = 0; e < kE; ++e) { accr[e] = 0.f; accn[e] = 0.f; }

    const float4 z4 = make_float4(0.f, 0.f, 0.f, 0.f);
    #pragma unroll
    for (int c = 0; c < 4; ++c) {
        const int d0 = c * 256 + lane * 4;
        const float4 xv = *(const float4*)(xr + d0);
        *(float4*)(outr + d0) = z4;          // fused zero_out
        short4 bv;
        bv.x = (short)f2bf(xv.x); bv.y = (short)f2bf(xv.y);
        bv.z = (short)f2bf(xv.z); bv.w = (short)f2bf(xv.w);
        *(short4*)(xbr + d0) = bv;
        const float xs[4] = {xv.x, xv.y, xv.z, xv.w};
        #pragma unroll
        for (int j = 0; j < 4; ++j) {
            const float4* wr4 = (const float4*)(Wr + (size_t)(d0 + j) * kE);
            const float4* wn4 = (const float4*)(Wn + (size_t)(d0 + j) * kE);
            const float4 r0 = wr4[0], r1 = wr4[1];
            const float4 m0 = wn4[0], m1 = wn4[1];
            const float xj = xs[j];
            accr[0] += xj * r0.x; accr[1] += xj * r0.y; accr[2] += xj * r0.z; accr[3] += xj * r0.w;
            accr[4] += xj * r1.x; accr[5] += xj * r1.y; accr[6] += xj * r1.z; accr[7] += xj * r1.w;
            accn[0] += xj * m0.x; accn[1] += xj * m0.y; accn[2] += xj * m0.z; accn[3] += xj * m0.w;
            accn[4] += xj * m1.x; accn[5] += xj * m1.y; accn[6] += xj * m1.z; accn[7] += xj * m1.w;
        }
    }
    #pragma unroll
    for (int e = 0; e < kE; ++e) {
        #pragma unroll
        for (int off = 32; off >= 1; off >>= 1) {
            accr[e] += __shfl_xor(accr[e], off, 64);
            accn[e] += __shfl_xor(accn[e], off, 64);
        }
    }
    if (lane == 0) {
        float noisy[kE];
        #pragma unroll
        for (int e = 0; e < kE; ++e) {
            const float lg = accr[e] + br[e];
            const float nl = accn[e] + bn[e];
            const float sp = fmaxf(nl, 0.f) + log1pf(expf(-fabsf(nl)));
            noisy[e] = lg + noise_raw[(size_t)n * kE + e] * sp;
        }
        int i0 = 0;
        #pragma unroll
        for (int e = 1; e < kE; ++e) if (noisy[e] > noisy[i0]) i0 = e;
        int i1 = (i0 == 0) ? 1 : 0;
        #pragma unroll
        for (int e = 0; e < kE; ++e) if (e != i0 && noisy[e] > noisy[i1]) i1 = e;
        const float ex = expf(noisy[i1] - noisy[i0]);
        topIdx[n] = make_int2(i0, i1);
        topProb[n] = make_float2(1.f / (1.f + ex), ex / (1.f + ex));
    }
}

// ---------------- dispatch: 4-wave two-pass stable compaction ----------------
__global__ __launch_bounds__(256) void moe_dispatch(
    const int2* __restrict__ topIdx, const float2* __restrict__ topProb,
    int* __restrict__ tokList, float* __restrict__ gateList, int* __restrict__ cnt)
{
    const int e = blockIdx.x;
    const int lane = threadIdx.x & 63;
    const int wq = threadIdx.x >> 6;        // 0..3
    const int tpw = kN / 4;
    const unsigned long long below = (lane == 0) ? 0ull : ((~0ull) >> (64 - lane));
    __shared__ int cw[4];

    int mycnt = 0;
    for (int it = 0; it < tpw / 64; ++it) {
        const int n = wq * tpw + it * 64 + lane;
        const int2 ti = topIdx[n];
        const bool sel = (ti.x == e) || (ti.y == e);
        mycnt += __popcll(__ballot(sel));
    }
    if (lane == 0) cw[wq] = mycnt;
    __syncthreads();
    int base = 0;
    #pragma unroll
    for (int q = 0; q < 4; ++q) if (q < wq) base += cw[q];

    for (int it = 0; it < tpw / 64; ++it) {
        const int n = wq * tpw + it * 64 + lane;
        const int2 ti = topIdx[n];
        const float2 tp = topProb[n];
        const bool sel = (ti.x == e) || (ti.y == e);
        const float g = (ti.x == e) ? tp.x : tp.y;
        const unsigned long long m = __ballot(sel);
        if (sel) {
            const int slot = base + __popcll(m & below);
            if (slot < kCap) { tokList[e * kCap + slot] = n; gateList[e * kCap + slot] = g; }
        }
        base += __popcll(m);
    }
    if (threadIdx.x == 0) {
        int tot = cw[0] + cw[1] + cw[2] + cw[3];
        cnt[e] = tot < kCap ? tot : kCap;
    }
}

// L2-locality block remap (verified r7/r8). Requires (gx*gy) % 8 == 0.
static __device__ __forceinline__ void remap_mn(int gx, int& mblk, int& nblk)
{
    const int l = blockIdx.y * gx + blockIdx.x;
    const int xcd = l & 7;
    const int pos = l >> 3;
    nblk = pos % gx;
    mblk = xcd + 8 * (pos / gx);
}

// ===== 256x256 BK=64 GEMM body, A DIRECT-FROM-GLOBAL (registers), B via LDS =====
// One WAITV + one barrier per K-tile. B double-buffered (r20 staging verbatim);
// A-fragments are per-lane 16B global loads from L2-resident panels (remap).
// Issue-order fences make WAITV(8) exact: drains everything except the 8
// just-issued A-prefetch loads (incl. B(t+1) stages -> next RD_B safe).
#define WAITV(N) asm volatile("s_waitcnt vmcnt(" #N ")" ::: "memory")
#define BARRIER_FENCE() do { __builtin_amdgcn_s_barrier(); asm volatile("" ::: "memory"); } while (0)

#define RD_Bf(DST, NS)                                                       \
    _Pragma("unroll")                                                        \
    for (int n_ = 0; n_ < 2; ++n_) {                                         \
        const int r_ = (wcol + ((NS) * 2 + n_) * 16 + l15) * 64;             \
        DST[n_][0] = *(const short8*)&Bs[buf][r_ + cbu0];                    \
        DST[n_][1] = *(const short8*)&Bs[buf][r_ + cbu1];                    \
    }
#define LD_A(DST, MS, KOFF)                                                  \
    _Pragma("unroll")                                                        \
    for (int m_ = 0; m_ < 4; ++m_)                                           \
        _Pragma("unroll")                                                    \
        for (int kk_ = 0; kk_ < 2; ++kk_)                                    \
            DST[m_][kk_] = *(const short8*)(aRow[(MS) * 4 + m_] + (KOFF) + kk_ * 32 + g * 8);
#define QMFMA(AF, BF, MS, NS)                                                \
    do {                                                                     \
        __builtin_amdgcn_s_setprio(1);                                       \
        _Pragma("unroll")                                                    \
        for (int kk_ = 0; kk_ < 2; ++kk_)                                    \
            _Pragma("unroll")                                                \
            for (int m_ = 0; m_ < 4; ++m_)                                   \
                _Pragma("unroll")                                            \
                for (int n_ = 0; n_ < 2; ++n_)                               \
                    acc[(MS) * 4 + m_][(NS) * 2 + n_] =                      \
                        __builtin_amdgcn_mfma_f32_16x16x32_bf16(             \
                            AF[m_][kk_], BF[n_][kk_],                        \
                            acc[(MS) * 4 + m_][(NS) * 2 + n_], 0, 0, 0);     \
        __builtin_amdgcn_s_setprio(0);                                       \
    } while (0)

#define KTILE_ADIRECT()                                                            \
    do {                                                                           \
        const int buf = t & 1, nb = buf ^ 1, t1 = t + 1;                           \
        const bool iss = (t1 < nt);                                                \
        RD_Bf(fb0, 0); RD_Bf(fb1, 1);               /* 8 ds_read from Bs[buf] */   \
        if (iss) { stB(0, nb, t1); stB(1, nb, t1); }  /* 4 gload_lds -> nb */      \
        QMFMA(fa0, fb0, 0, 0);                                                     \
        QMFMA(fa0, fb1, 0, 1);                                                     \
        LD_A(fa1, 1, t * 64);                                                      \
        QMFMA(fa1, fb0, 1, 0);                                                     \
        QMFMA(fa1, fb1, 1, 1);                                                     \
        asm volatile("" ::: "memory");              /* older mem ops pinned */     \
        if (iss) { LD_A(fa0, 0, t1 * 64); WAITV(8); } else { WAITV(0); }           \
        BARRIER_FENCE();                                                           \
    } while (0)

// ================= FFN pass 1: H = relu(Xg @ W1[e] + b1[e]) =================
__global__ __launch_bounds__(512, 2) void moe_ffn1_g(
    const unsigned short* __restrict__ xb, const unsigned short* __restrict__ W1t,
    const float* __restrict__ b1,
    const int* __restrict__ tokList, const int* __restrict__ cnt,
    unsigned short* __restrict__ Hbuf, int e_base)
{
    const int e = e_base + blockIdx.z;
    const int count = cnt[e];
    int mblk, nblk;
    remap_mn((int)gridDim.x, mblk, nblk);
    const int m0 = mblk * 256;
    if (m0 >= count) return;
    const int n0 = nblk * 256;

    __shared__ unsigned short shmem[128 * 264];          // 66 KB; Bs[2] aliases front
    auto Bs = reinterpret_cast<unsigned short (*)[256 * 64]>(shmem);

    const int tid = (int)threadIdx.x, lane = tid & 63, w = tid >> 6;
    const int wm = w >> 2, wn = w & 3;
    const int wrow = wm * 128, wcol = wn * 64;
    const int l15 = lane & 15, g = lane >> 4;
    const int rswz = l15 & 7;
    const int cbu0 = ((0 + g) ^ rswz) * 8;
    const int cbu1 = ((4 + g) ^ rswz) * 8;

    const int* tok = tokList + e * kCap;
    const unsigned short* We = W1t + (size_t)e * kD * kH;   // [kH][kD]

    // A row pointers (token gather), k-contiguous global reads
    const unsigned short* aRow[8];
    #pragma unroll
    for (int j = 0; j < 8; ++j) {
        int r = m0 + wrow + j * 16 + l15;
        if (r >= count) r = count - 1;
        aRow[j] = xb + (size_t)tok[r] * kD;
    }

    // B staging (r20 verbatim)
    const unsigned short* bS[2][2];
    unsigned bD[2][2];
    #pragma unroll
    for (int ns = 0; ns < 2; ++ns)
        #pragma unroll
        for (int ld = 0; ld < 2; ++ld) {
            const int flat = (wm * 2 + ld) * 64 + lane;          // [0,256)
            const int rl = wn * 64 + ns * 32 + (flat >> 3);      // tile-local B row
            const int c = (flat & 7) ^ (rl & 7);
            bS[ns][ld] = We + (size_t)(n0 + rl) * kD + c * 8;
            bD[ns][ld] = (wn * 64 + ns * 32) * 64 + (wm * 2 + ld) * 512;
        }

    f32x4 acc[8][4] = {};
    short8 fa0[4][2], fa1[4][2], fb0[2][2], fb1[2][2];

    auto stB = [&](int ns, int nb, int t1) {
        gload_lds16(bS[ns][0] + t1 * 64, &Bs[nb][bD[ns][0]]);
        gload_lds16(bS[ns][1] + t1 * 64, &Bs[nb][bD[ns][1]]);
    };

    constexpr int nt = kD / 64;   // 16
    stB(0, 0, 0); stB(1, 0, 0);
    WAITV(0);
    BARRIER_FENCE();
    LD_A(fa0, 0, 0);

    for (int t = 0; t < nt; ++t) {
        KTILE_ADIRECT();
    }

    // ---- coalesced H store via LDS tile [128][264] (r20-verified) ----
    const float* be = b1 + (size_t)e * kH + n0;
    unsigned short* H = Hbuf + (size_t)blockIdx.z * kCap * kH;
    unsigned short* tile = shmem;
    __syncthreads();
    #pragma unroll
    for (int p = 0; p < 2; ++p) {
        if (wm == p) {
            #pragma unroll
            for (int mm = 0; mm < 8; ++mm)
                #pragma unroll
                for (int i = 0; i < 4; ++i) {
                    const int rl = mm * 16 + g * 4 + i;
                    #pragma unroll
                    for (int nn = 0; nn < 4; ++nn) {
                        const int c = wcol + nn * 16 + l15;
                        tile[rl * 264 + c] = f2bf(fmaxf(acc[mm][nn][i] + be[c], 0.f));
                    }
                }
        }
        __syncthreads();
        #pragma unroll
        for (int j = 0; j < 8; ++j) {
            const int rl = j * 16 + w * 2 + (lane >> 5);
            const int r = m0 + p * 128 + rl;
            const int ch = lane & 31;
            if (r < count) {
                const short8 v = *(const short8*)&tile[rl * 264 + ch * 8];
                *(short8*)(H + (size_t)r * kH + n0 + ch * 8) = v;
            }
        }
        __syncthreads();
    }
}

// ================= FFN pass 2 + combine =================
__global__ __launch_bounds__(512, 2) void moe_ffn2_g(
    const unsigned short* __restrict__ Hbuf, const unsigned short* __restrict__ W2t,
    const float* __restrict__ b2,
    const int* __restrict__ tokList, const float* __restrict__ gateList,
    const int* __restrict__ cnt, float* __restrict__ out, int e_base)
{
    const int e = e_base + blockIdx.z;
    const int count = cnt[e];
    int mblk, nblk;
    remap_mn((int)gridDim.x, mblk, nblk);
    const int m0 = mblk * 256;
    if (m0 >= count) return;
    const int n0 = nblk * 256;

    __shared__ unsigned short shmem[2 * 256 * 64];       // 64 KB: Bs[2]
    auto Bs = reinterpret_cast<unsigned short (*)[256 * 64]>(shmem);

    const int tid = (int)threadIdx.x, lane = tid & 63, w = tid >> 6;
    const int wm = w >> 2, wn = w & 3;
    const int wrow = wm * 128, wcol = wn * 64;
    const int l15 = lane & 15, g = lane >> 4;
    const int rswz = l15 & 7;
    const int cbu0 = ((0 + g) ^ rswz) * 8;
    const int cbu1 = ((4 + g) ^ rswz) * 8;

    const unsigned short* H = Hbuf + (size_t)blockIdx.z * kCap * kH;
    const unsigned short* We = W2t + (size_t)e * kH * kD;   // [kD][kH]

    const unsigned short* aRow[8];
    #pragma unroll
    for (int j = 0; j < 8; ++j) {
        int r = m0 + wrow + j * 16 + l15;
        if (r >= count) r = count - 1;                     // junk rows masked in epilogue
        aRow[j] = H + (size_t)r * kH;
    }

    const unsigned short* bS[2][2];
    unsigned bD[2][2];
    #pragma unroll
    for (int ns = 0; ns < 2; ++ns)
        #pragma unroll
        for (int ld = 0; ld < 2; ++ld) {
            const int flat = (wm * 2 + ld) * 64 + lane;
            const int rl = wn * 64 + ns * 32 + (flat >> 3);
            const int c = (flat & 7) ^ (rl & 7);
            bS[ns][ld] = We + (size_t)(n0 + rl) * kH + c * 8;
            bD[ns][ld] = (wn * 64 + ns * 32) * 64 + (wm * 2 + ld) * 512;
        }

    f32x4 acc[8][4] = {};
    short8 fa0[4][2], fa1[4][2], fb0[2][2], fb1[2][2];

    auto stB = [&](int ns, int nb, int t1) {
        gload_lds16(bS[ns][0] + t1 * 64, &Bs[nb][bD[ns][0]]);
        gload_lds16(bS[ns][1] + t1 * 64, &Bs[nb][bD[ns][1]]);
    };

    constexpr int nt = kH / 64;   // 64
    stB(0, 0, 0); stB(1, 0, 0);
    WAITV(0);
    BARRIER_FENCE();
    LD_A(fa0, 0, 0);

    for (int t = 0; t < nt; ++t) {
        KTILE_ADIRECT();
    }

    const float* be = b2 + (size_t)e * kD + n0;
    const int* tok = tokList + e * kCap;
    const float* gate = gateList + e * kCap;
    #pragma unroll
    for (int mm = 0; mm < 8; ++mm) {
        #pragma unroll
        for (int i = 0; i < 4; ++i) {
            const int r = m0 + wrow + mm * 16 + g * 4 + i;
            if (r >= count) continue;
            const int tokn = tok[r];
            const float gr = gate[r];
            float* orow = out + (size_t)tokn * kD + n0;
            #pragma unroll
            for (int nn = 0; nn < 4; ++nn) {
                const int c = wcol + nn * 16 + l15;
                atomicAdd(orow + c, (acc[mm][nn][i] + be[c]) * gr);   // <=2 addends: deterministic
            }
        }
    }
}

// ---------------- launch ----------------
extern "C" void kernel_launch(void* const* d_in, const int* in_sizes, int n_in,
                              void* d_out, int out_size, void* d_ws, size_t ws_size,
                              hipStream_t stream)
{
    const float* x         = (const float*)d_in[0];
    const float* noise_raw = (const float*)d_in[1];
    const float* Wr        = (const float*)d_in[2];
    const float* br        = (const float*)d_in[3];
    const float* Wn        = (const float*)d_in[4];
    const float* bn        = (const float*)d_in[5];
    const float* W1        = (const float*)d_in[6];
    const float* b1        = (const float*)d_in[7];
    const float* W2        = (const float*)d_in[8];
    const float* b2        = (const float*)d_in[9];
    float* out = (float*)d_out;

    char* ws = (char*)d_ws;
    size_t off = 0;
    auto alloc = [&](size_t bytes) -> void* {
        void* p = ws + off;
        off = (off + bytes + 255) & ~(size_t)255;
        return p;
    };
    int2*   topIdx   = (int2*)  alloc((size_t)kN * sizeof(int2));
    float2* topProb  = (float2*)alloc((size_t)kN * sizeof(float2));
    int*    tokList  = (int*)   alloc((size_t)kE * kCap * sizeof(int));
    float*  gateList = (float*) alloc((size_t)kE * kCap * sizeof(float));
    int*    cnt      = (int*)   alloc((size_t)kE * sizeof(int));

    unsigned short* xb  = (unsigned short*)alloc((size_t)kN * kD * 2);        // 32 MB
    unsigned short* W1t = (unsigned short*)alloc((size_t)kE * kD * kH * 2);   // 64 MB
    unsigned short* W2t = (unsigned short*)alloc((size_t)kE * kH * kD * 2);   // 64 MB

    const size_t HB = (size_t)kCap * kH * 2;   // 32 MB / expert
    size_t rem = (ws_size > off) ? ws_size - off : 0;
    int G = (int)(rem / HB);
    if (G > kE) G = kE;
    if (G < 1) G = 1;
    unsigned short* Hbuf = (unsigned short*)(ws + off);

    moe_router<<<kN / 4, 256, 0, stream>>>(x, noise_raw, Wr, br, Wn, bn, topIdx, topProb, xb, out);
    moe_dispatch<<<kE, 256, 0, stream>>>(topIdx, topProb, tokList, gateList, cnt);
    moe_tcvt2<<<dim3(1024, 1, 2 * kE), 256, 0, stream>>>(W1, W1t, W2, W2t);

    for (int e0 = 0; e0 < kE; e0 += G) {
        const int gz = (kE - e0 < G) ? (kE - e0) : G;
        moe_ffn1_g<<<dim3(kH / 256, kCap / 256, gz), 512, 0, stream>>>(
            xb, W1t, b1, tokList, cnt, Hbuf, e0);
        moe_ffn2_g<<<dim3(kD / 256, kCap / 256, gz), 512, 0, stream>>>(
            Hbuf, W2t, b2, tokList, gateList, cnt, out, e0);
    }
}

// Round 22
// 955.760 us; speedup vs baseline: 1.6497x; 1.6497x over previous
//
#include <hip/hip_runtime.h>
#include <hip/hip_bf16.h>

namespace {
constexpr int kD = 1024, kE = 8, kH = 4096;
constexpr int kN = 16384;     // B*T tokens
constexpr int kCap = 4096;    // N*TOP_K/E * CAPACITY_FACTOR
}

typedef __attribute__((ext_vector_type(8))) short short8;
typedef __attribute__((ext_vector_type(4))) float f32x4;

static __device__ __forceinline__ unsigned short f2bf(float f) {
    __hip_bfloat16 h = __float2bfloat16(f);   // RNE
    unsigned short s;
    __builtin_memcpy(&s, &h, 2);
    return s;
}

static __device__ __forceinline__ void gload_lds16(const unsigned short* g, unsigned short* l) {
    __builtin_amdgcn_global_load_lds(
        (const __attribute__((address_space(1))) unsigned int*)g,
        (__attribute__((address_space(3))) unsigned int*)l, 16, 0, 0);
}

// ---------------- fused transpose+convert for W1 AND W2 (one launch) ----------------
__global__ __launch_bounds__(256) void moe_tcvt2(
    const float* __restrict__ W1, unsigned short* __restrict__ W1t,
    const float* __restrict__ W2, unsigned short* __restrict__ W2t)
{
    const int z = blockIdx.z;
    const float* src;
    unsigned short* dst;
    int R, C, bx, by;
    if (z < kE) {
        src = W1 + (size_t)z * kD * kH; dst = W1t + (size_t)z * kD * kH;
        R = kD; C = kH; bx = blockIdx.x % (kH / 64); by = blockIdx.x / (kH / 64);
    } else {
        src = W2 + (size_t)(z - kE) * kH * kD; dst = W2t + (size_t)(z - kE) * kH * kD;
        R = kH; C = kD; bx = blockIdx.x % (kD / 64); by = blockIdx.x / (kD / 64);
    }
    const int c0 = bx * 64, r0 = by * 64;
    __shared__ float t[64][68];
    const int tid = (int)threadIdx.x;
    const int tr = tid >> 2;
    const int tc = (tid & 3) * 16;
    #pragma unroll
    for (int j = 0; j < 4; ++j) {
        const float4 v = *(const float4*)(src + (size_t)(r0 + tr) * C + c0 + tc + j * 4);
        *(float4*)&t[tr][tc + j * 4] = v;
    }
    __syncthreads();
    unsigned short o[16];
    #pragma unroll
    for (int j = 0; j < 16; ++j) o[j] = f2bf(t[tc + j][tr]);
    unsigned short* dp = dst + (size_t)(c0 + tr) * R + r0 + tc;
    *(short8*)dp = *(const short8*)&o[0];
    *(short8*)(dp + 8) = *(const short8*)&o[8];
}

// ---------------- router (fused x->bf16 emit + out zeroing) ----------------
__global__ __launch_bounds__(256) void moe_router(
    const float* __restrict__ x, const float* __restrict__ noise_raw,
    const float* __restrict__ Wr, const float* __restrict__ br,
    const float* __restrict__ Wn, const float* __restrict__ bn,
    int2* __restrict__ topIdx, float2* __restrict__ topProb,
    unsigned short* __restrict__ xb, float* __restrict__ out)
{
    const int wave = threadIdx.x >> 6;
    const int lane = threadIdx.x & 63;
    const int n = blockIdx.x * 4 + wave;
    const float* xr = x + (size_t)n * kD;
    unsigned short* xbr = xb + (size_t)n * kD;
    float* outr = out + (size_t)n * kD;

    float accr[kE], accn[kE];
    #pragma unroll
    for (int e = 0; e < kE; ++e) { accr[e] = 0.f; accn[e] = 0.f; }

    const float4 z4 = make_float4(0.f, 0.f, 0.f, 0.f);
    #pragma unroll
    for (int c = 0; c < 4; ++c) {
        const int d0 = c * 256 + lane * 4;
        const float4 xv = *(const float4*)(xr + d0);
        *(float4*)(outr + d0) = z4;          // fused zero_out
        short4 bv;
        bv.x = (short)f2bf(xv.x); bv.y = (short)f2bf(xv.y);
        bv.z = (short)f2bf(xv.z); bv.w = (short)f2bf(xv.w);
        *(short4*)(xbr + d0) = bv;
        const float xs[4] = {xv.x, xv.y, xv.z, xv.w};
        #pragma unroll
        for (int j = 0; j < 4; ++j) {
            const float4* wr4 = (const float4*)(Wr + (size_t)(d0 + j) * kE);
            const float4* wn4 = (const float4*)(Wn + (size_t)(d0 + j) * kE);
            const float4 r0 = wr4[0], r1 = wr4[1];
            const float4 m0 = wn4[0], m1 = wn4[1];
            const float xj = xs[j];
            accr[0] += xj * r0.x; accr[1] += xj * r0.y; accr[2] += xj * r0.z; accr[3] += xj * r0.w;
            accr[4] += xj * r1.x; accr[5] += xj * r1.y; accr[6] += xj * r1.z; accr[7] += xj * r1.w;
            accn[0] += xj * m0.x; accn[1] += xj * m0.y; accn[2] += xj * m0.z; accn[3] += xj * m0.w;
            accn[4] += xj * m1.x; accn[5] += xj * m1.y; accn[6] += xj * m1.z; accn[7] += xj * m1.w;
        }
    }
    #pragma unroll
    for (int e = 0; e < kE; ++e) {
        #pragma unroll
        for (int off = 32; off >= 1; off >>= 1) {
            accr[e] += __shfl_xor(accr[e], off, 64);
            accn[e] += __shfl_xor(accn[e], off, 64);
        }
    }
    if (lane == 0) {
        float noisy[kE];
        #pragma unroll
        for (int e = 0; e < kE; ++e) {
            const float lg = accr[e] + br[e];
            const float nl = accn[e] + bn[e];
            const float sp = fmaxf(nl, 0.f) + log1pf(expf(-fabsf(nl)));
            noisy[e] = lg + noise_raw[(size_t)n * kE + e] * sp;
        }
        int i0 = 0;
        #pragma unroll
        for (int e = 1; e < kE; ++e) if (noisy[e] > noisy[i0]) i0 = e;
        int i1 = (i0 == 0) ? 1 : 0;
        #pragma unroll
        for (int e = 0; e < kE; ++e) if (e != i0 && noisy[e] > noisy[i1]) i1 = e;
        const float ex = expf(noisy[i1] - noisy[i0]);
        topIdx[n] = make_int2(i0, i1);
        topProb[n] = make_float2(1.f / (1.f + ex), ex / (1.f + ex));
    }
}

// ---------------- dispatch: 4-wave two-pass stable compaction ----------------
__global__ __launch_bounds__(256) void moe_dispatch(
    const int2* __restrict__ topIdx, const float2* __restrict__ topProb,
    int* __restrict__ tokList, float* __restrict__ gateList, int* __restrict__ cnt)
{
    const int e = blockIdx.x;
    const int lane = threadIdx.x & 63;
    const int wq = threadIdx.x >> 6;        // 0..3
    const int tpw = kN / 4;
    const unsigned long long below = (lane == 0) ? 0ull : ((~0ull) >> (64 - lane));
    __shared__ int cw[4];

    int mycnt = 0;
    for (int it = 0; it < tpw / 64; ++it) {
        const int n = wq * tpw + it * 64 + lane;
        const int2 ti = topIdx[n];
        const bool sel = (ti.x == e) || (ti.y == e);
        mycnt += __popcll(__ballot(sel));
    }
    if (lane == 0) cw[wq] = mycnt;
    __syncthreads();
    int base = 0;
    #pragma unroll
    for (int q = 0; q < 4; ++q) if (q < wq) base += cw[q];

    for (int it = 0; it < tpw / 64; ++it) {
        const int n = wq * tpw + it * 64 + lane;
        const int2 ti = topIdx[n];
        const float2 tp = topProb[n];
        const bool sel = (ti.x == e) || (ti.y == e);
        const float g = (ti.x == e) ? tp.x : tp.y;
        const unsigned long long m = __ballot(sel);
        if (sel) {
            const int slot = base + __popcll(m & below);
            if (slot < kCap) { tokList[e * kCap + slot] = n; gateList[e * kCap + slot] = g; }
        }
        base += __popcll(m);
    }
    if (threadIdx.x == 0) {
        int tot = cw[0] + cw[1] + cw[2] + cw[3];
        cnt[e] = tot < kCap ? tot : kCap;
    }
}

// L2-locality block remap (verified r7/r8). Requires (gx*gy) % 8 == 0.
static __device__ __forceinline__ void remap_mn(int gx, int& mblk, int& nblk)
{
    const int l = blockIdx.y * gx + blockIdx.x;
    const int xcd = l & 7;
    const int pos = l >> 3;
    nblk = pos % gx;
    mblk = xcd + 8 * (pos / gx);
}

// ===== 256x256 BK=64 GEMM body, r18 schedule (3 barriers/K-tile, operand =====
// ===== carry + early-issue + counted vmcnt). Verified best.               =====
#define WAITV(N) asm volatile("s_waitcnt vmcnt(" #N ")" ::: "memory")
#define BARRIER_FENCE() do { __builtin_amdgcn_s_barrier(); asm volatile("" ::: "memory"); } while (0)

#define RD_A(DST, MS)                                                        \
    _Pragma("unroll")                                                        \
    for (int m_ = 0; m_ < 4; ++m_) {                                         \
        const int r_ = (wrow + ((MS) * 4 + m_) * 16 + l15) * 64;             \
        DST[m_][0] = *(const short8*)&As[buf][r_ + cbu0];                    \
        DST[m_][1] = *(const short8*)&As[buf][r_ + cbu1];                    \
    }
#define RD_B(DST, NS)                                                        \
    _Pragma("unroll")                                                        \
    for (int n_ = 0; n_ < 2; ++n_) {                                         \
        const int r_ = (wcol + ((NS) * 2 + n_) * 16 + l15) * 64;             \
        DST[n_][0] = *(const short8*)&Bs[buf][r_ + cbu0];                    \
        DST[n_][1] = *(const short8*)&Bs[buf][r_ + cbu1];                    \
    }
#define QMFMA(AF, BF, MS, NS)                                                \
    do {                                                                     \
        __builtin_amdgcn_s_setprio(1);                                       \
        _Pragma("unroll")                                                    \
        for (int kk_ = 0; kk_ < 2; ++kk_)                                    \
            _Pragma("unroll")                                                \
            for (int m_ = 0; m_ < 4; ++m_)                                   \
                _Pragma("unroll")                                            \
                for (int n_ = 0; n_ < 2; ++n_)                               \
                    acc[(MS) * 4 + m_][(NS) * 2 + n_] =                      \
                        __builtin_amdgcn_mfma_f32_16x16x32_bf16(             \
                            AF[m_][kk_], BF[n_][kk_],                        \
                            acc[(MS) * 4 + m_][(NS) * 2 + n_], 0, 0, 0);     \
        __builtin_amdgcn_s_setprio(0);                                       \
    } while (0)

#define KTILE_BODY()                                                               \
    do {                                                                           \
        const int buf = t & 1, nb = buf ^ 1, t1 = t + 1;                           \
        const bool iss = (t1 < nt);                                                \
        short8 a0[4][2], a1[4][2], b0[2][2], b1[2][2];                             \
        /* P1: read A0,B0; issue A0(t+1)+B0(t+1) */                                \
        RD_A(a0, 0); RD_B(b0, 0);                                                  \
        if (iss) { stA(0, nb, t1); stB(0, nb, t1); }                               \
        if (iss) { WAITV(6); } else { WAITV(2); }                                  \
        BARRIER_FENCE();                                                           \
        QMFMA(a0, b0, 0, 0);                                                       \
        /* P2: read A1 (keep b0); issue A1(t+1) */                                 \
        RD_A(a1, 1);                                                               \
        if (iss) stA(1, nb, t1);                                                   \
        if (iss) { WAITV(6); } else { WAITV(0); }                                  \
        BARRIER_FENCE();                                                           \
        QMFMA(a1, b0, 1, 0);                                                       \
        /* P3 (merged): read B1; issue B1(t+1); drain A0,B0(t+1); Q11+Q01 */       \
        RD_B(b1, 1);                                                               \
        if (iss) stB(1, nb, t1);                                                   \
        if (iss) { WAITV(4); } else { WAITV(0); }                                  \
        BARRIER_FENCE();                                                           \
        QMFMA(a1, b1, 1, 1);                                                       \
        QMFMA(a0, b1, 0, 1);                                                       \
    } while (0)

// ================= FFN pass 1: H = relu(Xg @ W1[e] + b1[e]) =================
// Epilogue: LDS-staged coalesced H store (fixes 2.8x HBM write amplification).
__global__ __launch_bounds__(512, 2) void moe_ffn1_g(
    const unsigned short* __restrict__ xb, const unsigned short* __restrict__ W1t,
    const float* __restrict__ b1,
    const int* __restrict__ tokList, const int* __restrict__ cnt,
    unsigned short* __restrict__ Hbuf, int e_base)
{
    const int e = e_base + blockIdx.z;
    const int count = cnt[e];
    int mblk, nblk;
    remap_mn((int)gridDim.x, mblk, nblk);
    const int m0 = mblk * 256;
    if (m0 >= count) return;
    const int n0 = nblk * 256;

    __shared__ unsigned short shmem[4 * 256 * 64];   // 128 KB: As[2] | Bs[2]; reused by epilogue
    auto As = reinterpret_cast<unsigned short (*)[256 * 64]>(shmem);
    auto Bs = reinterpret_cast<unsigned short (*)[256 * 64]>(shmem + 2 * 256 * 64);

    const int tid = (int)threadIdx.x, lane = tid & 63, w = tid >> 6;
    const int wm = w >> 2, wg = w & 3, wn = w & 3;
    const int wrow = wm * 128, wcol = wn * 64;
    const int l15 = lane & 15, g = lane >> 4;
    const int rswz = l15 & 7;
    const int cbu0 = ((0 + g) ^ rswz) * 8;    // kk=0 chunk, ushort offset
    const int cbu1 = ((4 + g) ^ rswz) * 8;    // kk=1 chunk

    const int* tok = tokList + e * kCap;
    const unsigned short* We = W1t + (size_t)e * kD * kH;   // [kH][kD]

    const unsigned short* aS[2][2];
    const unsigned short* bS[2][2];
    unsigned aD[2][2], bD[2][2];
    #pragma unroll
    for (int ms = 0; ms < 2; ++ms)
        #pragma unroll
        for (int ld = 0; ld < 2; ++ld) {
            const int flat = (wg * 2 + ld) * 64 + lane;          // [0,512)
            const int rl = wm * 128 + ms * 64 + (flat >> 3);     // tile-local A row
            const int c = (flat & 7) ^ (rl & 7);
            int am = m0 + rl; if (am >= count) am = count - 1;
            aS[ms][ld] = xb + (size_t)tok[am] * kD + c * 8;
            aD[ms][ld] = (wm * 128 + ms * 64) * 64 + (wg * 2 + ld) * 512;
        }
    #pragma unroll
    for (int ns = 0; ns < 2; ++ns)
        #pragma unroll
        for (int ld = 0; ld < 2; ++ld) {
            const int flat = (wm * 2 + ld) * 64 + lane;          // [0,256)
            const int rl = wn * 64 + ns * 32 + (flat >> 3);      // tile-local B row
            const int c = (flat & 7) ^ (rl & 7);
            bS[ns][ld] = We + (size_t)(n0 + rl) * kD + c * 8;
            bD[ns][ld] = (wn * 64 + ns * 32) * 64 + (wm * 2 + ld) * 512;
        }

    f32x4 acc[8][4] = {};

    auto stA = [&](int ms, int nb, int t1) {
        gload_lds16(aS[ms][0] + t1 * 64, &As[nb][aD[ms][0]]);
        gload_lds16(aS[ms][1] + t1 * 64, &As[nb][aD[ms][1]]);
    };
    auto stB = [&](int ns, int nb, int t1) {
        gload_lds16(bS[ns][0] + t1 * 64, &Bs[nb][bD[ns][0]]);
        gload_lds16(bS[ns][1] + t1 * 64, &Bs[nb][bD[ns][1]]);
    };

    constexpr int nt = kD / 64;   // 16
    stA(0, 0, 0); stB(0, 0, 0); stA(1, 0, 0); stB(1, 0, 0);
    WAITV(4);
    BARRIER_FENCE();

    for (int t = 0; t < nt; ++t) {
        KTILE_BODY();
    }

    // ---- coalesced H store via LDS tile [128][264] (row stride 528 B = 33*16) ----
    const float* be = b1 + (size_t)e * kH + n0;
    unsigned short* H = Hbuf + (size_t)blockIdx.z * kCap * kH;
    unsigned short* tile = shmem;
    __syncthreads();                          // all LDS frag reads done
    #pragma unroll
    for (int p = 0; p < 2; ++p) {
        if (wm == p) {                        // row-half owner writes its acc
            #pragma unroll
            for (int mm = 0; mm < 8; ++mm)
                #pragma unroll
                for (int i = 0; i < 4; ++i) {
                    const int rl = mm * 16 + g * 4 + i;
                    #pragma unroll
                    for (int nn = 0; nn < 4; ++nn) {
                        const int c = wcol + nn * 16 + l15;
                        tile[rl * 264 + c] = f2bf(fmaxf(acc[mm][nn][i] + be[c], 0.f));
                    }
                }
        }
        __syncthreads();
        // copy out: 16 rows/iter (2 rows per wave, 16 lanes x short8 per row)
        #pragma unroll
        for (int j = 0; j < 8; ++j) {
            const int rl = j * 16 + w * 2 + (lane >> 5);
            const int r = m0 + p * 128 + rl;
            const int ch = lane & 31;
            if (r < count) {
                const short8 v = *(const short8*)&tile[rl * 264 + ch * 8];
                *(short8*)(H + (size_t)r * kH + n0 + ch * 8) = v;
            }
        }
        __syncthreads();                      // WAR: tile reused by next pass
    }
}

// ================= FFN pass 2 + combine =================
__global__ __launch_bounds__(512, 2) void moe_ffn2_g(
    const unsigned short* __restrict__ Hbuf, const unsigned short* __restrict__ W2t,
    const float* __restrict__ b2,
    const int* __restrict__ tokList, const float* __restrict__ gateList,
    const int* __restrict__ cnt, float* __restrict__ out, int e_base)
{
    const int e = e_base + blockIdx.z;
    const int count = cnt[e];
    int mblk, nblk;
    remap_mn((int)gridDim.x, mblk, nblk);
    const int m0 = mblk * 256;
    if (m0 >= count) return;
    const int n0 = nblk * 256;

    __shared__ unsigned short As[2][256 * 64];
    __shared__ unsigned short Bs[2][256 * 64];

    const int tid = (int)threadIdx.x, lane = tid & 63, w = tid >> 6;
    const int wm = w >> 2, wg = w & 3, wn = w & 3;
    const int wrow = wm * 128, wcol = wn * 64;
    const int l15 = lane & 15, g = lane >> 4;
    const int rswz = l15 & 7;
    const int cbu0 = ((0 + g) ^ rswz) * 8;
    const int cbu1 = ((4 + g) ^ rswz) * 8;

    const unsigned short* H = Hbuf + (size_t)blockIdx.z * kCap * kH;
    const unsigned short* We = W2t + (size_t)e * kH * kD;   // [kD][kH]

    const unsigned short* aS[2][2];
    const unsigned short* bS[2][2];
    unsigned aD[2][2], bD[2][2];
    #pragma unroll
    for (int ms = 0; ms < 2; ++ms)
        #pragma unroll
        for (int ld = 0; ld < 2; ++ld) {
            const int flat = (wg * 2 + ld) * 64 + lane;
            const int rl = wm * 128 + ms * 64 + (flat >> 3);
            const int c = (flat & 7) ^ (rl & 7);
            aS[ms][ld] = H + (size_t)(m0 + rl) * kH + c * 8;   // junk rows masked in epilogue
            aD[ms][ld] = (wm * 128 + ms * 64) * 64 + (wg * 2 + ld) * 512;
        }
    #pragma unroll
    for (int ns = 0; ns < 2; ++ns)
        #pragma unroll
        for (int ld = 0; ld < 2; ++ld) {
            const int flat = (wm * 2 + ld) * 64 + lane;
            const int rl = wn * 64 + ns * 32 + (flat >> 3);
            const int c = (flat & 7) ^ (rl & 7);
            bS[ns][ld] = We + (size_t)(n0 + rl) * kH + c * 8;
            bD[ns][ld] = (wn * 64 + ns * 32) * 64 + (wm * 2 + ld) * 512;
        }

    f32x4 acc[8][4] = {};

    auto stA = [&](int ms, int nb, int t1) {
        gload_lds16(aS[ms][0] + t1 * 64, &As[nb][aD[ms][0]]);
        gload_lds16(aS[ms][1] + t1 * 64, &As[nb][aD[ms][1]]);
    };
    auto stB = [&](int ns, int nb, int t1) {
        gload_lds16(bS[ns][0] + t1 * 64, &Bs[nb][bD[ns][0]]);
        gload_lds16(bS[ns][1] + t1 * 64, &Bs[nb][bD[ns][1]]);
    };

    constexpr int nt = kH / 64;   // 64
    stA(0, 0, 0); stB(0, 0, 0); stA(1, 0, 0); stB(1, 0, 0);
    WAITV(4);
    BARRIER_FENCE();

    for (int t = 0; t < nt; ++t) {
        KTILE_BODY();
    }

    const float* be = b2 + (size_t)e * kD + n0;
    const int* tok = tokList + e * kCap;
    const float* gate = gateList + e * kCap;
    #pragma unroll
    for (int mm = 0; mm < 8; ++mm) {
        #pragma unroll
        for (int i = 0; i < 4; ++i) {
            const int r = m0 + wrow + mm * 16 + g * 4 + i;
            if (r >= count) continue;
            const int tokn = tok[r];
            const float gr = gate[r];
            float* orow = out + (size_t)tokn * kD + n0;
            #pragma unroll
            for (int nn = 0; nn < 4; ++nn) {
                const int c = wcol + nn * 16 + l15;
                atomicAdd(orow + c, (acc[mm][nn][i] + be[c]) * gr);   // <=2 addends: deterministic
            }
        }
    }
}

// ---------------- launch ----------------
extern "C" void kernel_launch(void* const* d_in, const int* in_sizes, int n_in,
                              void* d_out, int out_size, void* d_ws, size_t ws_size,
                              hipStream_t stream)
{
    const float* x         = (const float*)d_in[0];
    const float* noise_raw = (const float*)d_in[1];
    const float* Wr        = (const float*)d_in[2];
    const float* br        = (const float*)d_in[3];
    const float* Wn        = (const float*)d_in[4];
    const float* bn        = (const float*)d_in[5];
    const float* W1        = (const float*)d_in[6];
    const float* b1        = (const float*)d_in[7];
    const float* W2        = (const float*)d_in[8];
    const float* b2        = (const float*)d_in[9];
    float* out = (float*)d_out;

    char* ws = (char*)d_ws;
    size_t off = 0;
    auto alloc = [&](size_t bytes) -> void* {
        void* p = ws + off;
        off = (off + bytes + 255) & ~(size_t)255;
        return p;
    };
    int2*   topIdx   = (int2*)  alloc((size_t)kN * sizeof(int2));
    float2* topProb  = (float2*)alloc((size_t)kN * sizeof(float2));
    int*    tokList  = (int*)   alloc((size_t)kE * kCap * sizeof(int));
    float*  gateList = (float*) alloc((size_t)kE * kCap * sizeof(float));
    int*    cnt      = (int*)   alloc((size_t)kE * sizeof(int));

    unsigned short* xb  = (unsigned short*)alloc((size_t)kN * kD * 2);        // 32 MB
    unsigned short* W1t = (unsigned short*)alloc((size_t)kE * kD * kH * 2);   // 64 MB
    unsigned short* W2t = (unsigned short*)alloc((size_t)kE * kH * kD * 2);   // 64 MB

    const size_t HB = (size_t)kCap * kH * 2;   // 32 MB / expert
    size_t rem = (ws_size > off) ? ws_size - off : 0;
    int G = (int)(rem / HB);
    if (G > kE) G = kE;
    if (G < 1) G = 1;
    unsigned short* Hbuf = (unsigned short*)(ws + off);

    moe_router<<<kN / 4, 256, 0, stream>>>(x, noise_raw, Wr, br, Wn, bn, topIdx, topProb, xb, out);
    moe_dispatch<<<kE, 256, 0, stream>>>(topIdx, topProb, tokList, gateList, cnt);
    moe_tcvt2<<<dim3(1024, 1, 2 * kE), 256, 0, stream>>>(W1, W1t, W2, W2t);

    for (int e0 = 0; e0 < kE; e0 += G) {
        const int gz = (kE - e0 < G) ? (kE - e0) : G;
        moe_ffn1_g<<<dim3(kH / 256, kCap / 256, gz), 512, 0, stream>>>(
            xb, W1t, b1, tokList, cnt, Hbuf, e0);
        moe_ffn2_g<<<dim3(kD / 256, kCap / 256, gz), 512, 0, stream>>>(
            Hbuf, W2t, b2, tokList, gateList, cnt, out, e0);
    }
}

// Round 23
// 932.756 us; speedup vs baseline: 1.6904x; 1.0247x over previous
//
#include <hip/hip_runtime.h>
#include <hip/hip_bf16.h>

namespace {
constexpr int kD = 1024, kE = 8, kH = 4096;
constexpr int kN = 16384;     // B*T tokens
constexpr int kCap = 4096;    // N*TOP_K/E * CAPACITY_FACTOR
}

typedef __attribute__((ext_vector_type(8))) short short8;
typedef __attribute__((ext_vector_type(4))) float f32x4;

static __device__ __forceinline__ unsigned short f2bf(float f) {
    __hip_bfloat16 h = __float2bfloat16(f);   // RNE
    unsigned short s;
    __builtin_memcpy(&s, &h, 2);
    return s;
}

static __device__ __forceinline__ void gload_lds16(const unsigned short* g, unsigned short* l) {
    __builtin_amdgcn_global_load_lds(
        (const __attribute__((address_space(1))) unsigned int*)g,
        (__attribute__((address_space(3))) unsigned int*)l, 16, 0, 0);
}

// ---------------- fused transpose+convert for W1 AND W2 (one launch) ----------------
__global__ __launch_bounds__(256) void moe_tcvt2(
    const float* __restrict__ W1, unsigned short* __restrict__ W1t,
    const float* __restrict__ W2, unsigned short* __restrict__ W2t)
{
    const int z = blockIdx.z;
    const float* src;
    unsigned short* dst;
    int R, C, bx, by;
    if (z < kE) {
        src = W1 + (size_t)z * kD * kH; dst = W1t + (size_t)z * kD * kH;
        R = kD; C = kH; bx = blockIdx.x % (kH / 64); by = blockIdx.x / (kH / 64);
    } else {
        src = W2 + (size_t)(z - kE) * kH * kD; dst = W2t + (size_t)(z - kE) * kH * kD;
        R = kH; C = kD; bx = blockIdx.x % (kD / 64); by = blockIdx.x / (kD / 64);
    }
    const int c0 = bx * 64, r0 = by * 64;
    __shared__ float t[64][68];
    const int tid = (int)threadIdx.x;
    const int tr = tid >> 2;
    const int tc = (tid & 3) * 16;
    #pragma unroll
    for (int j = 0; j < 4; ++j) {
        const float4 v = *(const float4*)(src + (size_t)(r0 + tr) * C + c0 + tc + j * 4);
        *(float4*)&t[tr][tc + j * 4] = v;
    }
    __syncthreads();
    unsigned short o[16];
    #pragma unroll
    for (int j = 0; j < 16; ++j) o[j] = f2bf(t[tc + j][tr]);
    unsigned short* dp = dst + (size_t)(c0 + tr) * R + r0 + tc;
    *(short8*)dp = *(const short8*)&o[0];
    *(short8*)(dp + 8) = *(const short8*)&o[8];
}

// ---------------- router (fused x->bf16 emit + out zeroing) ----------------
__global__ __launch_bounds__(256) void moe_router(
    const float* __restrict__ x, const float* __restrict__ noise_raw,
    const float* __restrict__ Wr, const float* __restrict__ br,
    const float* __restrict__ Wn, const float* __restrict__ bn,
    int2* __restrict__ topIdx, float2* __restrict__ topProb,
    unsigned short* __restrict__ xb, float* __restrict__ out)
{
    const int wave = threadIdx.x >> 6;
    const int lane = threadIdx.x & 63;
    const int n = blockIdx.x * 4 + wave;
    const float* xr = x + (size_t)n * kD;
    unsigned short* xbr = xb + (size_t)n * kD;
    float* outr = out + (size_t)n * kD;

    float accr[kE], accn[kE];
    #pragma unroll
    for (int e = 0; e < kE; ++e) { accr[e] = 0.f; accn[e] = 0.f; }

    const float4 z4 = make_float4(0.f, 0.f, 0.f, 0.f);
    #pragma unroll
    for (int c = 0; c < 4; ++c) {
        const int d0 = c * 256 + lane * 4;
        const float4 xv = *(const float4*)(xr + d0);
        *(float4*)(outr + d0) = z4;          // fused zero_out
        short4 bv;
        bv.x = (short)f2bf(xv.x); bv.y = (short)f2bf(xv.y);
        bv.z = (short)f2bf(xv.z); bv.w = (short)f2bf(xv.w);
        *(short4*)(xbr + d0) = bv;
        const float xs[4] = {xv.x, xv.y, xv.z, xv.w};
        #pragma unroll
        for (int j = 0; j < 4; ++j) {
            const float4* wr4 = (const float4*)(Wr + (size_t)(d0 + j) * kE);
            const float4* wn4 = (const float4*)(Wn + (size_t)(d0 + j) * kE);
            const float4 r0 = wr4[0], r1 = wr4[1];
            const float4 m0 = wn4[0], m1 = wn4[1];
            const float xj = xs[j];
            accr[0] += xj * r0.x; accr[1] += xj * r0.y; accr[2] += xj * r0.z; accr[3] += xj * r0.w;
            accr[4] += xj * r1.x; accr[5] += xj * r1.y; accr[6] += xj * r1.z; accr[7] += xj * r1.w;
            accn[0] += xj * m0.x; accn[1] += xj * m0.y; accn[2] += xj * m0.z; accn[3] += xj * m0.w;
            accn[4] += xj * m1.x; accn[5] += xj * m1.y; accn[6] += xj * m1.z; accn[7] += xj * m1.w;
        }
    }
    #pragma unroll
    for (int e = 0; e < kE; ++e) {
        #pragma unroll
        for (int off = 32; off >= 1; off >>= 1) {
            accr[e] += __shfl_xor(accr[e], off, 64);
            accn[e] += __shfl_xor(accn[e], off, 64);
        }
    }
    if (lane == 0) {
        float noisy[kE];
        #pragma unroll
        for (int e = 0; e < kE; ++e) {
            const float lg = accr[e] + br[e];
            const float nl = accn[e] + bn[e];
            const float sp = fmaxf(nl, 0.f) + log1pf(expf(-fabsf(nl)));
            noisy[e] = lg + noise_raw[(size_t)n * kE + e] * sp;
        }
        int i0 = 0;
        #pragma unroll
        for (int e = 1; e < kE; ++e) if (noisy[e] > noisy[i0]) i0 = e;
        int i1 = (i0 == 0) ? 1 : 0;
        #pragma unroll
        for (int e = 0; e < kE; ++e) if (e != i0 && noisy[e] > noisy[i1]) i1 = e;
        const float ex = expf(noisy[i1] - noisy[i0]);
        topIdx[n] = make_int2(i0, i1);
        topProb[n] = make_float2(1.f / (1.f + ex), ex / (1.f + ex));
    }
}

// ---------------- dispatch: 16-wave two-pass stable compaction ----------------
// Wave wq owns tokens [wq*kN/16, (wq+1)*kN/16); pass 1 counts, LDS prefix,
// pass 2 writes. Slot assignment identical to 1-wave version (stable order).
__global__ __launch_bounds__(1024) void moe_dispatch(
    const int2* __restrict__ topIdx, const float2* __restrict__ topProb,
    int* __restrict__ tokList, float* __restrict__ gateList, int* __restrict__ cnt)
{
    const int e = blockIdx.x;
    const int lane = threadIdx.x & 63;
    const int wq = threadIdx.x >> 6;        // 0..15
    const int tpw = kN / 16;                // 1024 tokens per wave
    const unsigned long long below = (lane == 0) ? 0ull : ((~0ull) >> (64 - lane));
    __shared__ int cw[16];

    int mycnt = 0;
    for (int it = 0; it < tpw / 64; ++it) {   // 16 iters
        const int n = wq * tpw + it * 64 + lane;
        const int2 ti = topIdx[n];
        const bool sel = (ti.x == e) || (ti.y == e);
        mycnt += __popcll(__ballot(sel));
    }
    if (lane == 0) cw[wq] = mycnt;
    __syncthreads();
    int base = 0;
    #pragma unroll
    for (int q = 0; q < 16; ++q) if (q < wq) base += cw[q];

    for (int it = 0; it < tpw / 64; ++it) {
        const int n = wq * tpw + it * 64 + lane;
        const int2 ti = topIdx[n];
        const float2 tp = topProb[n];
        const bool sel = (ti.x == e) || (ti.y == e);
        const float g = (ti.x == e) ? tp.x : tp.y;
        const unsigned long long m = __ballot(sel);
        if (sel) {
            const int slot = base + __popcll(m & below);
            if (slot < kCap) { tokList[e * kCap + slot] = n; gateList[e * kCap + slot] = g; }
        }
        base += __popcll(m);
    }
    if (threadIdx.x == 0) {
        int tot = 0;
        #pragma unroll
        for (int q = 0; q < 16; ++q) tot += cw[q];
        cnt[e] = tot < kCap ? tot : kCap;
    }
}

// L2-locality block remap (verified r7/r8). Requires (gx*gy) % 8 == 0.
static __device__ __forceinline__ void remap_mn(int gx, int& mblk, int& nblk)
{
    const int l = blockIdx.y * gx + blockIdx.x;
    const int xcd = l & 7;
    const int pos = l >> 3;
    nblk = pos % gx;
    mblk = xcd + 8 * (pos / gx);
}

// ===== 256x256 BK=64 GEMM body, r18 schedule (3 barriers/K-tile, operand =====
// ===== carry + early-issue + counted vmcnt). Verified best.               =====
#define WAITV(N) asm volatile("s_waitcnt vmcnt(" #N ")" ::: "memory")
#define BARRIER_FENCE() do { __builtin_amdgcn_s_barrier(); asm volatile("" ::: "memory"); } while (0)

#define RD_A(DST, MS)                                                        \
    _Pragma("unroll")                                                        \
    for (int m_ = 0; m_ < 4; ++m_) {                                         \
        const int r_ = (wrow + ((MS) * 4 + m_) * 16 + l15) * 64;             \
        DST[m_][0] = *(const short8*)&As[buf][r_ + cbu0];                    \
        DST[m_][1] = *(const short8*)&As[buf][r_ + cbu1];                    \
    }
#define RD_B(DST, NS)                                                        \
    _Pragma("unroll")                                                        \
    for (int n_ = 0; n_ < 2; ++n_) {                                         \
        const int r_ = (wcol + ((NS) * 2 + n_) * 16 + l15) * 64;             \
        DST[n_][0] = *(const short8*)&Bs[buf][r_ + cbu0];                    \
        DST[n_][1] = *(const short8*)&Bs[buf][r_ + cbu1];                    \
    }
#define QMFMA(AF, BF, MS, NS)                                                \
    do {                                                                     \
        __builtin_amdgcn_s_setprio(1);                                       \
        _Pragma("unroll")                                                    \
        for (int kk_ = 0; kk_ < 2; ++kk_)                                    \
            _Pragma("unroll")                                                \
            for (int m_ = 0; m_ < 4; ++m_)                                   \
                _Pragma("unroll")                                            \
                for (int n_ = 0; n_ < 2; ++n_)                               \
                    acc[(MS) * 4 + m_][(NS) * 2 + n_] =                      \
                        __builtin_amdgcn_mfma_f32_16x16x32_bf16(             \
                            AF[m_][kk_], BF[n_][kk_],                        \
                            acc[(MS) * 4 + m_][(NS) * 2 + n_], 0, 0, 0);     \
        __builtin_amdgcn_s_setprio(0);                                       \
    } while (0)

#define KTILE_BODY()                                                               \
    do {                                                                           \
        const int buf = t & 1, nb = buf ^ 1, t1 = t + 1;                           \
        const bool iss = (t1 < nt);                                                \
        short8 a0[4][2], a1[4][2], b0[2][2], b1[2][2];                             \
        /* P1: read A0,B0; issue A0(t+1)+B0(t+1) */                                \
        RD_A(a0, 0); RD_B(b0, 0);                                                  \
        if (iss) { stA(0, nb, t1); stB(0, nb, t1); }                               \
        if (iss) { WAITV(6); } else { WAITV(2); }                                  \
        BARRIER_FENCE();                                                           \
        QMFMA(a0, b0, 0, 0);                                                       \
        /* P2: read A1 (keep b0); issue A1(t+1) */                                 \
        RD_A(a1, 1);                                                               \
        if (iss) stA(1, nb, t1);                                                   \
        if (iss) { WAITV(6); } else { WAITV(0); }                                  \
        BARRIER_FENCE();                                                           \
        QMFMA(a1, b0, 1, 0);                                                       \
        /* P3 (merged): read B1; issue B1(t+1); drain A0,B0(t+1); Q11+Q01 */       \
        RD_B(b1, 1);                                                               \
        if (iss) stB(1, nb, t1);                                                   \
        if (iss) { WAITV(4); } else { WAITV(0); }                                  \
        BARRIER_FENCE();                                                           \
        QMFMA(a1, b1, 1, 1);                                                       \
        QMFMA(a0, b1, 0, 1);                                                       \
    } while (0)

// ================= FFN pass 1: H = relu(Xg @ W1[e] + b1[e]) =================
// Epilogue: LDS-staged coalesced H store (fixes 2.8x HBM write amplification).
__global__ __launch_bounds__(512, 2) void moe_ffn1_g(
    const unsigned short* __restrict__ xb, const unsigned short* __restrict__ W1t,
    const float* __restrict__ b1,
    const int* __restrict__ tokList, const int* __restrict__ cnt,
    unsigned short* __restrict__ Hbuf, int e_base)
{
    const int e = e_base + blockIdx.z;
    const int count = cnt[e];
    int mblk, nblk;
    remap_mn((int)gridDim.x, mblk, nblk);
    const int m0 = mblk * 256;
    if (m0 >= count) return;
    const int n0 = nblk * 256;

    __shared__ unsigned short shmem[4 * 256 * 64];   // 128 KB: As[2] | Bs[2]; reused by epilogue
    auto As = reinterpret_cast<unsigned short (*)[256 * 64]>(shmem);
    auto Bs = reinterpret_cast<unsigned short (*)[256 * 64]>(shmem + 2 * 256 * 64);

    const int tid = (int)threadIdx.x, lane = tid & 63, w = tid >> 6;
    const int wm = w >> 2, wg = w & 3, wn = w & 3;
    const int wrow = wm * 128, wcol = wn * 64;
    const int l15 = lane & 15, g = lane >> 4;
    const int rswz = l15 & 7;
    const int cbu0 = ((0 + g) ^ rswz) * 8;    // kk=0 chunk, ushort offset
    const int cbu1 = ((4 + g) ^ rswz) * 8;    // kk=1 chunk

    const int* tok = tokList + e * kCap;
    const unsigned short* We = W1t + (size_t)e * kD * kH;   // [kH][kD]

    const unsigned short* aS[2][2];
    const unsigned short* bS[2][2];
    unsigned aD[2][2], bD[2][2];
    #pragma unroll
    for (int ms = 0; ms < 2; ++ms)
        #pragma unroll
        for (int ld = 0; ld < 2; ++ld) {
            const int flat = (wg * 2 + ld) * 64 + lane;          // [0,512)
            const int rl = wm * 128 + ms * 64 + (flat >> 3);     // tile-local A row
            const int c = (flat & 7) ^ (rl & 7);
            int am = m0 + rl; if (am >= count) am = count - 1;
            aS[ms][ld] = xb + (size_t)tok[am] * kD + c * 8;
            aD[ms][ld] = (wm * 128 + ms * 64) * 64 + (wg * 2 + ld) * 512;
        }
    #pragma unroll
    for (int ns = 0; ns < 2; ++ns)
        #pragma unroll
        for (int ld = 0; ld < 2; ++ld) {
            const int flat = (wm * 2 + ld) * 64 + lane;          // [0,256)
            const int rl = wn * 64 + ns * 32 + (flat >> 3);      // tile-local B row
            const int c = (flat & 7) ^ (rl & 7);
            bS[ns][ld] = We + (size_t)(n0 + rl) * kD + c * 8;
            bD[ns][ld] = (wn * 64 + ns * 32) * 64 + (wm * 2 + ld) * 512;
        }

    f32x4 acc[8][4] = {};

    auto stA = [&](int ms, int nb, int t1) {
        gload_lds16(aS[ms][0] + t1 * 64, &As[nb][aD[ms][0]]);
        gload_lds16(aS[ms][1] + t1 * 64, &As[nb][aD[ms][1]]);
    };
    auto stB = [&](int ns, int nb, int t1) {
        gload_lds16(bS[ns][0] + t1 * 64, &Bs[nb][bD[ns][0]]);
        gload_lds16(bS[ns][1] + t1 * 64, &Bs[nb][bD[ns][1]]);
    };

    constexpr int nt = kD / 64;   // 16
    stA(0, 0, 0); stB(0, 0, 0); stA(1, 0, 0); stB(1, 0, 0);
    WAITV(4);
    BARRIER_FENCE();

    for (int t = 0; t < nt; ++t) {
        KTILE_BODY();
    }

    // ---- coalesced H store via LDS tile [128][264] (row stride 528 B = 33*16) ----
    const float* be = b1 + (size_t)e * kH + n0;
    unsigned short* H = Hbuf + (size_t)blockIdx.z * kCap * kH;
    unsigned short* tile = shmem;
    __syncthreads();                          // all LDS frag reads done
    #pragma unroll
    for (int p = 0; p < 2; ++p) {
        if (wm == p) {                        // row-half owner writes its acc
            #pragma unroll
            for (int mm = 0; mm < 8; ++mm)
                #pragma unroll
                for (int i = 0; i < 4; ++i) {
                    const int rl = mm * 16 + g * 4 + i;
                    #pragma unroll
                    for (int nn = 0; nn < 4; ++nn) {
                        const int c = wcol + nn * 16 + l15;
                        tile[rl * 264 + c] = f2bf(fmaxf(acc[mm][nn][i] + be[c], 0.f));
                    }
                }
        }
        __syncthreads();
        // copy out: 16 rows/iter (2 rows per wave, 16 lanes x short8 per row)
        #pragma unroll
        for (int j = 0; j < 8; ++j) {
            const int rl = j * 16 + w * 2 + (lane >> 5);
            const int r = m0 + p * 128 + rl;
            const int ch = lane & 31;
            if (r < count) {
                const short8 v = *(const short8*)&tile[rl * 264 + ch * 8];
                *(short8*)(H + (size_t)r * kH + n0 + ch * 8) = v;
            }
        }
        __syncthreads();                      // WAR: tile reused by next pass
    }
}

// ================= FFN pass 2 + combine =================
__global__ __launch_bounds__(512, 2) void moe_ffn2_g(
    const unsigned short* __restrict__ Hbuf, const unsigned short* __restrict__ W2t,
    const float* __restrict__ b2,
    const int* __restrict__ tokList, const float* __restrict__ gateList,
    const int* __restrict__ cnt, float* __restrict__ out, int e_base)
{
    const int e = e_base + blockIdx.z;
    const int count = cnt[e];
    int mblk, nblk;
    remap_mn((int)gridDim.x, mblk, nblk);
    const int m0 = mblk * 256;
    if (m0 >= count) return;
    const int n0 = nblk * 256;

    __shared__ unsigned short As[2][256 * 64];
    __shared__ unsigned short Bs[2][256 * 64];

    const int tid = (int)threadIdx.x, lane = tid & 63, w = tid >> 6;
    const int wm = w >> 2, wg = w & 3, wn = w & 3;
    const int wrow = wm * 128, wcol = wn * 64;
    const int l15 = lane & 15, g = lane >> 4;
    const int rswz = l15 & 7;
    const int cbu0 = ((0 + g) ^ rswz) * 8;
    const int cbu1 = ((4 + g) ^ rswz) * 8;

    const unsigned short* H = Hbuf + (size_t)blockIdx.z * kCap * kH;
    const unsigned short* We = W2t + (size_t)e * kH * kD;   // [kD][kH]

    const unsigned short* aS[2][2];
    const unsigned short* bS[2][2];
    unsigned aD[2][2], bD[2][2];
    #pragma unroll
    for (int ms = 0; ms < 2; ++ms)
        #pragma unroll
        for (int ld = 0; ld < 2; ++ld) {
            const int flat = (wg * 2 + ld) * 64 + lane;
            const int rl = wm * 128 + ms * 64 + (flat >> 3);
            const int c = (flat & 7) ^ (rl & 7);
            aS[ms][ld] = H + (size_t)(m0 + rl) * kH + c * 8;   // junk rows masked in epilogue
            aD[ms][ld] = (wm * 128 + ms * 64) * 64 + (wg * 2 + ld) * 512;
        }
    #pragma unroll
    for (int ns = 0; ns < 2; ++ns)
        #pragma unroll
        for (int ld = 0; ld < 2; ++ld) {
            const int flat = (wm * 2 + ld) * 64 + lane;
            const int rl = wn * 64 + ns * 32 + (flat >> 3);
            const int c = (flat & 7) ^ (rl & 7);
            bS[ns][ld] = We + (size_t)(n0 + rl) * kH + c * 8;
            bD[ns][ld] = (wn * 64 + ns * 32) * 64 + (wm * 2 + ld) * 512;
        }

    f32x4 acc[8][4] = {};

    auto stA = [&](int ms, int nb, int t1) {
        gload_lds16(aS[ms][0] + t1 * 64, &As[nb][aD[ms][0]]);
        gload_lds16(aS[ms][1] + t1 * 64, &As[nb][aD[ms][1]]);
    };
    auto stB = [&](int ns, int nb, int t1) {
        gload_lds16(bS[ns][0] + t1 * 64, &Bs[nb][bD[ns][0]]);
        gload_lds16(bS[ns][1] + t1 * 64, &Bs[nb][bD[ns][1]]);
    };

    constexpr int nt = kH / 64;   // 64
    stA(0, 0, 0); stB(0, 0, 0); stA(1, 0, 0); stB(1, 0, 0);
    WAITV(4);
    BARRIER_FENCE();

    for (int t = 0; t < nt; ++t) {
        KTILE_BODY();
    }

    const float* be = b2 + (size_t)e * kD + n0;
    const int* tok = tokList + e * kCap;
    const float* gate = gateList + e * kCap;
    #pragma unroll
    for (int mm = 0; mm < 8; ++mm) {
        #pragma unroll
        for (int i = 0; i < 4; ++i) {
            const int r = m0 + wrow + mm * 16 + g * 4 + i;
            if (r >= count) continue;
            const int tokn = tok[r];
            const float gr = gate[r];
            float* orow = out + (size_t)tokn * kD + n0;
            #pragma unroll
            for (int nn = 0; nn < 4; ++nn) {
                const int c = wcol + nn * 16 + l15;
                atomicAdd(orow + c, (acc[mm][nn][i] + be[c]) * gr);   // <=2 addends: deterministic
            }
        }
    }
}

// ---------------- launch ----------------
extern "C" void kernel_launch(void* const* d_in, const int* in_sizes, int n_in,
                              void* d_out, int out_size, void* d_ws, size_t ws_size,
                              hipStream_t stream)
{
    const float* x         = (const float*)d_in[0];
    const float* noise_raw = (const float*)d_in[1];
    const float* Wr        = (const float*)d_in[2];
    const float* br        = (const float*)d_in[3];
    const float* Wn        = (const float*)d_in[4];
    const float* bn        = (const float*)d_in[5];
    const float* W1        = (const float*)d_in[6];
    const float* b1        = (const float*)d_in[7];
    const float* W2        = (const float*)d_in[8];
    const float* b2        = (const float*)d_in[9];
    float* out = (float*)d_out;

    char* ws = (char*)d_ws;
    size_t off = 0;
    auto alloc = [&](size_t bytes) -> void* {
        void* p = ws + off;
        off = (off + bytes + 255) & ~(size_t)255;
        return p;
    };
    int2*   topIdx   = (int2*)  alloc((size_t)kN * sizeof(int2));
    float2* topProb  = (float2*)alloc((size_t)kN * sizeof(float2));
    int*    tokList  = (int*)   alloc((size_t)kE * kCap * sizeof(int));
    float*  gateList = (float*) alloc((size_t)kE * kCap * sizeof(float));
    int*    cnt      = (int*)   alloc((size_t)kE * sizeof(int));

    unsigned short* xb  = (unsigned short*)alloc((size_t)kN * kD * 2);        // 32 MB
    unsigned short* W1t = (unsigned short*)alloc((size_t)kE * kD * kH * 2);   // 64 MB
    unsigned short* W2t = (unsigned short*)alloc((size_t)kE * kH * kD * 2);   // 64 MB

    const size_t HB = (size_t)kCap * kH * 2;   // 32 MB / expert
    size_t rem = (ws_size > off) ? ws_size - off : 0;
    int G = (int)(rem / HB);
    if (G > kE) G = kE;
    if (G < 1) G = 1;
    unsigned short* Hbuf = (unsigned short*)(ws + off);

    moe_router<<<kN / 4, 256, 0, stream>>>(x, noise_raw, Wr, br, Wn, bn, topIdx, topProb, xb, out);
    moe_dispatch<<<kE, 1024, 0, stream>>>(topIdx, topProb, tokList, gateList, cnt);
    moe_tcvt2<<<dim3(1024, 1, 2 * kE), 256, 0, stream>>>(W1, W1t, W2, W2t);

    for (int e0 = 0; e0 < kE; e0 += G) {
        const int gz = (kE - e0 < G) ? (kE - e0) : G;
        moe_ffn1_g<<<dim3(kH / 256, kCap / 256, gz), 512, 0, stream>>>(
            xb, W1t, b1, tokList, cnt, Hbuf, e0);
        moe_ffn2_g<<<dim3(kD / 256, kCap / 256, gz), 512, 0, stream>>>(
            Hbuf, W2t, b2, tokList, gateList, cnt, out, e0);
    }
}